// Round 9
// baseline (287.191 us; speedup 1.0000x reference)
//
#include <hip/hip_runtime.h>
#include <hip/hip_bf16.h>

#define PD 272            // padded expm dim (257 -> 272)
#define PD2 (PD*PD)       // 73984
#define D 256
#define BATCH 262144
#define NT (BATCH/16)     // 16384 16-row tiles
#define G 512             // gemm grid: 2 blocks/CU, 32 tiles/block
#define NSTEP (NT/G)      // 32

typedef __bf16 bf16x8 __attribute__((ext_vector_type(8)));
typedef float  f32x4  __attribute__((ext_vector_type(4)));

// ================= expm chain (fp32, 272-padded, 3 kernels) ==============
// ||M*dt|| ~ 1.6 -> degree-8 Paterson-Stockmeyer Taylor, remainder ~9e-4
// (matrix norm) << bf16 rounding of Phi. E = (c0I+c1M+c2M2+c3M3) + M4*W,
// W = c4I+c5M+c6M2+c7M3+c8M4, M4 = M2^2.

__device__ __forceinline__ float dotPD(const float* __restrict__ xr,
                                       const float* __restrict__ yc) {
    float a[16];
    #pragma unroll
    for (int u = 0; u < 16; ++u) a[u] = 0.f;
    #pragma unroll 2
    for (int k0 = 0; k0 < PD; k0 += 16) {
        #pragma unroll
        for (int u = 0; u < 16; ++u)
            a[u] = fmaf(xr[k0 + u], yc[(size_t)(k0 + u) * PD], a[u]);
    }
    float s = 0.f;
    #pragma unroll
    for (int u = 0; u < 16; ++u) s += a[u];
    return s;
}

// e1: Ms = M*dt (on the fly); M2 = Ms^2
__global__ void expm_mm1(const float* __restrict__ A, const float* __restrict__ b,
                         const int* __restrict__ t0, const int* __restrict__ tf,
                         float* __restrict__ Ms, float* __restrict__ M2) {
    int idx = blockIdx.x * blockDim.x + threadIdx.x;
    if (idx >= PD2) return;
    int i = idx / PD, j = idx - i * PD;
    float sc = (float)(tf[0] - t0[0]);
    float mv = 0.f;
    if (i < D && j < D) mv = A[i * D + j] * sc;
    else if (i < D && j == D) mv = b[i] * sc;
    Ms[idx] = mv;
    float acc = 0.f;
    if (i < D && j <= D) {
        const float* xr = A + (size_t)i * D;
        float a[16];
        #pragma unroll
        for (int u = 0; u < 16; ++u) a[u] = 0.f;
        if (j < D) {
            const float* yc = A + j;
            #pragma unroll 2
            for (int k0 = 0; k0 < D; k0 += 16) {
                #pragma unroll
                for (int u = 0; u < 16; ++u)
                    a[u] = fmaf(xr[k0 + u], yc[(size_t)(k0 + u) * D], a[u]);
            }
        } else {
            for (int k0 = 0; k0 < D; k0 += 16) {
                #pragma unroll
                for (int u = 0; u < 16; ++u)
                    a[u] = fmaf(xr[k0 + u], b[k0 + u], a[u]);
            }
        }
        float s = 0.f;
        #pragma unroll
        for (int u = 0; u < 16; ++u) s += a[u];
        acc = s * sc * sc;
    }
    M2[idx] = acc;
}

// e2: dual-dot off one shared M2-row stream:
//   M3 = M2*Ms, M4 = M2*M2, W = c4I+c5Ms+c6M2+c7M3+c8M4
__global__ void expm_mm2(const float* __restrict__ Ms, const float* __restrict__ M2,
                         float* __restrict__ M3, float* __restrict__ M4,
                         float* __restrict__ W) {
    int idx = blockIdx.x * blockDim.x + threadIdx.x;
    if (idx >= PD2) return;
    int i = idx / PD, j = idx - i * PD;
    const float* xr = M2 + (size_t)i * PD;
    const float* y3 = Ms + j;
    const float* y4 = M2 + j;
    float a3[8], a4[8];
    #pragma unroll
    for (int u = 0; u < 8; ++u) { a3[u] = 0.f; a4[u] = 0.f; }
    #pragma unroll 2
    for (int k0 = 0; k0 < PD; k0 += 8) {
        #pragma unroll
        for (int u = 0; u < 8; ++u) {
            float xv = xr[k0 + u];
            a3[u] = fmaf(xv, y3[(size_t)(k0 + u) * PD], a3[u]);
            a4[u] = fmaf(xv, y4[(size_t)(k0 + u) * PD], a4[u]);
        }
    }
    float v3 = ((a3[0]+a3[1])+(a3[2]+a3[3])) + ((a3[4]+a3[5])+(a3[6]+a3[7]));
    float v4 = ((a4[0]+a4[1])+(a4[2]+a4[3])) + ((a4[4]+a4[5])+(a4[6]+a4[7]));
    M3[idx] = v3;
    M4[idx] = v4;
    const float c4 = 1.f/24.f, c5 = 1.f/120.f, c6 = 1.f/720.f,
                c7 = 1.f/5040.f, c8 = 1.f/40320.f;
    float w = (i == j) ? c4 : 0.f;
    w = fmaf(c5, Ms[idx], w);
    w = fmaf(c6, M2[idx], w);
    w = fmaf(c7, v3, w);
    w = fmaf(c8, v4, w);
    W[idx] = w;
}

// e3: E = c0I+c1Ms+c2M2+c3M3 + M4*W; emit PhiB (bf16 [n][k]) + aff directly
__global__ void expm_mm3(const float* __restrict__ M4, const float* __restrict__ W,
                         const float* __restrict__ Ms, const float* __restrict__ M2,
                         const float* __restrict__ M3,
                         __bf16* __restrict__ PhiB, float* __restrict__ aff) {
    int idx = blockIdx.x * blockDim.x + threadIdx.x;
    if (idx >= PD2) return;
    int i = idx / PD, j = idx - i * PD;
    if (i >= D || j > D) return;
    float v = dotPD(M4 + (size_t)i * PD, W + j);
    float e = (i == j) ? 1.f : 0.f;
    e += Ms[idx];
    e = fmaf(0.5f, M2[idx], e);
    e = fmaf(1.f/6.f, M3[idx], e);
    e += v;
    if (j < D) PhiB[i * D + j] = (__bf16)e;
    else       aff[i] = e;
}

// ================= main GEMM =============================================
// out[m][n] = sum_k X[m][k]*Phi[n][k] + aff[n]
// NO LDS, NO barriers, NO waitcnt games. Block = 8 waves (512 thr), n-split
// 32 cols/wave, Phi frags pinned in registers (proven: VGPR=64 in R8).
// Each wave independently streams 16-row tiles, loading its MFMA X-fragments
// directly from global (16 x dwordx4 per step). The 8x intra-block read
// amplification is served by L1/L2 (tile is block-exclusive, 16 KB,
// L1-resident after first touch; aggregate demand ~23 TB/s < 34.5 TB/s L2
// ceiling). HBM stream is free-running with 16 waves/CU of TLP -- no
// barrier-lockstep drain gaps (the R8-counter-diagnosed cost).
__global__ __launch_bounds__(512, 4) void gemm_out(
    const float* __restrict__ X, const __bf16* __restrict__ PhiB,
    const float* __restrict__ aff, float* __restrict__ out) {
    const int lane = threadIdx.x & 63;
    const int wid  = threadIdx.x >> 6;   // 0..7
    const int col  = lane & 15;          // X row within tile = D-col (m)
    const int g    = lane >> 4;          // k-group
    const int n0   = wid * 32;
    const int bid  = blockIdx.x;

    // ---- Phi fragments: 2 n-tiles x 8 ks, pinned in registers ----
    f32x4 bfr[2][8];
    #pragma unroll
    for (int t4 = 0; t4 < 2; ++t4) {
        const char* bp = (const char*)PhiB + (size_t)2 * ((n0 + t4 * 16 + col) * D + g * 8);
        #pragma unroll
        for (int ks = 0; ks < 8; ++ks)
            bfr[t4][ks] = *(const f32x4*)(bp + 2 * ks * 32);
    }
    #pragma unroll
    for (int t4 = 0; t4 < 2; ++t4)
        #pragma unroll
        for (int ks = 0; ks < 8; ++ks)
            asm volatile("" : "+v"(bfr[t4][ks]));

    f32x4 avv[2];
    #pragma unroll
    for (int t4 = 0; t4 < 2; ++t4)
        avv[t4] = *(const f32x4*)(aff + n0 + t4 * 16 + 4 * g);
    #pragma unroll
    for (int t4 = 0; t4 < 2; ++t4) asm volatile("" : "+v"(avv[t4]));

    for (int i = 0; i < NSTEP; ++i) {
        const float* ap = X + ((size_t)(bid + (size_t)i * G) * 16 + col) * D + g * 8;

        // 16 independent dwordx4 loads for this tile's fragment set
        f32x4 lo[8], hi[8];
        #pragma unroll
        for (int ks = 0; ks < 8; ++ks) {
            lo[ks] = *(const f32x4*)(ap + ks * 32);
            hi[ks] = *(const f32x4*)(ap + ks * 32 + 4);
        }

        f32x4 acc0 = (f32x4){0.f, 0.f, 0.f, 0.f};
        f32x4 acc1 = (f32x4){0.f, 0.f, 0.f, 0.f};
        #pragma unroll
        for (int ks = 0; ks < 8; ++ks) {
            bf16x8 a;
            #pragma unroll
            for (int j = 0; j < 4; ++j) {
                a[j]     = (__bf16)lo[ks][j];
                a[4 + j] = (__bf16)hi[ks][j];
            }
            acc0 = __builtin_amdgcn_mfma_f32_16x16x32_bf16(
                __builtin_bit_cast(bf16x8, bfr[0][ks]), a, acc0, 0, 0, 0);
            acc1 = __builtin_amdgcn_mfma_f32_16x16x32_bf16(
                __builtin_bit_cast(bf16x8, bfr[1][ks]), a, acc1, 0, 0, 0);
        }

        // coalesced f32x4 stores (D layout: col = lane&15 = m, row = 4g+r = n)
        float* orow = out + ((size_t)(bid + (size_t)i * G) * 16 + col) * D + n0;
        *(f32x4*)(orow + 4 * g)      = acc0 + avv[0];
        *(f32x4*)(orow + 16 + 4 * g) = acc1 + avv[1];
    }
}

// ================= launch ================================================

extern "C" void kernel_launch(void* const* d_in, const int* in_sizes, int n_in,
                              void* d_out, int out_size, void* d_ws, size_t ws_size,
                              hipStream_t stream) {
    const float* X  = (const float*)d_in[0];
    const float* A  = (const float*)d_in[1];
    const float* b  = (const float*)d_in[2];
    const int*   t0 = (const int*)d_in[3];
    const int*   tf = (const int*)d_in[4];
    float* out = (float*)d_out;

    float* ws = (float*)d_ws;
    float* Ms = ws + 0 * PD2;
    float* M2 = ws + 1 * PD2;
    float* M3 = ws + 2 * PD2;
    float* M4 = ws + 3 * PD2;
    float* W  = ws + 4 * PD2;
    __bf16* PhiB = (__bf16*)(ws + 5 * PD2);
    float*  aff  = ws + 5 * PD2 + (D * D) / 2;

    const int g1 = (PD2 + 255) / 256;

    expm_mm1<<<g1, 256, 0, stream>>>(A, b, t0, tf, Ms, M2);
    expm_mm2<<<g1, 256, 0, stream>>>(Ms, M2, M3, M4, W);
    expm_mm3<<<g1, 256, 0, stream>>>(M4, W, Ms, M2, M3, PhiB, aff);

    gemm_out<<<G, 512, 0, stream>>>(X, PhiB, aff, out);
}

// Round 10
// 266.027 us; speedup vs baseline: 1.0796x; 1.0796x over previous
//
#include <hip/hip_runtime.h>
#include <hip/hip_bf16.h>

#define PD 272            // padded expm dim (257 -> 272)
#define PD2 (PD*PD)       // 73984
#define D 256
#define BATCH 262144
#define NT (BATCH/16)     // 16384 16-row tiles
#define G 512             // gemm grid: 2 blocks/CU, 32 tiles/block
#define NSTEP (NT/G)      // 32
#define REPS 2            // INSTRUMENTATION: keep gemm above the 152us fill
                          // kernels so rocprof top-5 shows its counters.

typedef __bf16 bf16x8 __attribute__((ext_vector_type(8)));
typedef float  f32x4  __attribute__((ext_vector_type(4)));

#define WAITV(n) asm volatile("s_waitcnt vmcnt(" #n ")" ::: "memory")

// ================= expm chain (fp32, 272-padded, 3 kernels) ==============
// ||M*dt|| ~ 1.6 -> degree-8 Paterson-Stockmeyer Taylor, remainder ~9e-4
// << bf16 rounding of Phi. E = (c0I+c1M+c2M2+c3M3) + M4*W,
// W = c4I+c5M+c6M2+c7M3+c8M4, M4 = M2^2.

__device__ __forceinline__ float dotPD(const float* __restrict__ xr,
                                       const float* __restrict__ yc) {
    float a[16];
    #pragma unroll
    for (int u = 0; u < 16; ++u) a[u] = 0.f;
    #pragma unroll 2
    for (int k0 = 0; k0 < PD; k0 += 16) {
        #pragma unroll
        for (int u = 0; u < 16; ++u)
            a[u] = fmaf(xr[k0 + u], yc[(size_t)(k0 + u) * PD], a[u]);
    }
    float s = 0.f;
    #pragma unroll
    for (int u = 0; u < 16; ++u) s += a[u];
    return s;
}

// e1: Ms = M*dt (on the fly); M2 = Ms^2
__global__ void expm_mm1(const float* __restrict__ A, const float* __restrict__ b,
                         const int* __restrict__ t0, const int* __restrict__ tf,
                         float* __restrict__ Ms, float* __restrict__ M2) {
    int idx = blockIdx.x * blockDim.x + threadIdx.x;
    if (idx >= PD2) return;
    int i = idx / PD, j = idx - i * PD;
    float sc = (float)(tf[0] - t0[0]);
    float mv = 0.f;
    if (i < D && j < D) mv = A[i * D + j] * sc;
    else if (i < D && j == D) mv = b[i] * sc;
    Ms[idx] = mv;
    float acc = 0.f;
    if (i < D && j <= D) {
        const float* xr = A + (size_t)i * D;
        float a[16];
        #pragma unroll
        for (int u = 0; u < 16; ++u) a[u] = 0.f;
        if (j < D) {
            const float* yc = A + j;
            #pragma unroll 2
            for (int k0 = 0; k0 < D; k0 += 16) {
                #pragma unroll
                for (int u = 0; u < 16; ++u)
                    a[u] = fmaf(xr[k0 + u], yc[(size_t)(k0 + u) * D], a[u]);
            }
        } else {
            for (int k0 = 0; k0 < D; k0 += 16) {
                #pragma unroll
                for (int u = 0; u < 16; ++u)
                    a[u] = fmaf(xr[k0 + u], b[k0 + u], a[u]);
            }
        }
        float s = 0.f;
        #pragma unroll
        for (int u = 0; u < 16; ++u) s += a[u];
        acc = s * sc * sc;
    }
    M2[idx] = acc;
}

// e2: dual-dot off one shared M2-row stream:
//   M3 = M2*Ms, M4 = M2*M2, W = c4I+c5Ms+c6M2+c7M3+c8M4
__global__ void expm_mm2(const float* __restrict__ Ms, const float* __restrict__ M2,
                         float* __restrict__ M3, float* __restrict__ M4,
                         float* __restrict__ W) {
    int idx = blockIdx.x * blockDim.x + threadIdx.x;
    if (idx >= PD2) return;
    int i = idx / PD, j = idx - i * PD;
    const float* xr = M2 + (size_t)i * PD;
    const float* y3 = Ms + j;
    const float* y4 = M2 + j;
    float a3[8], a4[8];
    #pragma unroll
    for (int u = 0; u < 8; ++u) { a3[u] = 0.f; a4[u] = 0.f; }
    #pragma unroll 2
    for (int k0 = 0; k0 < PD; k0 += 8) {
        #pragma unroll
        for (int u = 0; u < 8; ++u) {
            float xv = xr[k0 + u];
            a3[u] = fmaf(xv, y3[(size_t)(k0 + u) * PD], a3[u]);
            a4[u] = fmaf(xv, y4[(size_t)(k0 + u) * PD], a4[u]);
        }
    }
    float v3 = ((a3[0]+a3[1])+(a3[2]+a3[3])) + ((a3[4]+a3[5])+(a3[6]+a3[7]));
    float v4 = ((a4[0]+a4[1])+(a4[2]+a4[3])) + ((a4[4]+a4[5])+(a4[6]+a4[7]));
    M3[idx] = v3;
    M4[idx] = v4;
    const float c4 = 1.f/24.f, c5 = 1.f/120.f, c6 = 1.f/720.f,
                c7 = 1.f/5040.f, c8 = 1.f/40320.f;
    float w = (i == j) ? c4 : 0.f;
    w = fmaf(c5, Ms[idx], w);
    w = fmaf(c6, M2[idx], w);
    w = fmaf(c7, v3, w);
    w = fmaf(c8, v4, w);
    W[idx] = w;
}

// e3: E = c0I+c1Ms+c2M2+c3M3 + M4*W; emit PhiB (bf16 [n][k]) + aff directly
__global__ void expm_mm3(const float* __restrict__ M4, const float* __restrict__ W,
                         const float* __restrict__ Ms, const float* __restrict__ M2,
                         const float* __restrict__ M3,
                         __bf16* __restrict__ PhiB, float* __restrict__ aff) {
    int idx = blockIdx.x * blockDim.x + threadIdx.x;
    if (idx >= PD2) return;
    int i = idx / PD, j = idx - i * PD;
    if (i >= D || j > D) return;
    float v = dotPD(M4 + (size_t)i * PD, W + j);
    float e = (i == j) ? 1.f : 0.f;
    e += Ms[idx];
    e = fmaf(0.5f, M2[idx], e);
    e = fmaf(1.f/6.f, M3[idx], e);
    e += v;
    if (j < D) PhiB[i * D + j] = (__bf16)e;
    else       aff[i] = e;
}

// ================= main GEMM =============================================
// out[m][n] = sum_k X[m][k]*Phi[n][k] + aff[n]
// R6 structure + DEPTH-3 PREFETCH (R8 counters: load-MLP was the limiter --
// only ~16KB/CU outstanding vs ~22KB BW*latency product; ring-4 gives ~96KB).
// Block = 8 waves, n-split 32 cols/wave, Phi frags pinned (VGPR-cheap, R8).
// X in 4x16KB LDS ring via global_load_lds w=16 (XOR-preswizzled source).
// Step order (pinned): wait; barrier; stage(i+3); compute(i); stores(i).
// In-order vmem queue => exact waits: stage(i) done == vmcnt(4,6,8) prologue,
// (10) steady, (8,6) tail [derived in analysis; stage issued first-in-step].
__global__ __launch_bounds__(512, 4) void gemm_out(
    const float* __restrict__ X, const __bf16* __restrict__ PhiB,
    const float* __restrict__ aff, float* __restrict__ out) {
    __shared__ float lds[4][16 * 256];          // 4 x 16 KB ring

    const int lane = threadIdx.x & 63;
    const int wid  = threadIdx.x >> 6;   // 0..7
    const int col  = lane & 15;          // X row within tile = D-col (m)
    const int g    = lane >> 4;          // k-group
    const int n0   = wid * 32;
    const int bid  = blockIdx.x;
    const int xr   = (col & 7) << 4;

    // ---- Phi fragments: 2 n-tiles x 8 ks, pinned in registers ----
    f32x4 bfr[2][8];
    #pragma unroll
    for (int t4 = 0; t4 < 2; ++t4) {
        const char* bp = (const char*)PhiB + (size_t)2 * ((n0 + t4 * 16 + col) * D + g * 8);
        #pragma unroll
        for (int ks = 0; ks < 8; ++ks)
            bfr[t4][ks] = *(const f32x4*)(bp + 2 * ks * 32);
    }
    #pragma unroll
    for (int t4 = 0; t4 < 2; ++t4)
        #pragma unroll
        for (int ks = 0; ks < 8; ++ks)
            asm volatile("" : "+v"(bfr[t4][ks]));

    f32x4 avv[2];
    #pragma unroll
    for (int t4 = 0; t4 < 2; ++t4)
        avv[t4] = *(const f32x4*)(aff + n0 + t4 * 16 + 4 * g);
    #pragma unroll
    for (int t4 = 0; t4 < 2; ++t4) asm volatile("" : "+v"(avv[t4]));

    // stage tile i (tile id = bid + i*G) into ring buf i&3
    auto stage = [&](int i) __attribute__((always_inline)) {
        const char* src = (const char*)(X + (size_t)(bid + (size_t)i * G) * 4096);
        #pragma unroll
        for (int q = 0; q < 2; ++q) {
            int row = wid * 2 + q;
            const char* gp = src + row * 1024 + ((lane * 16) ^ ((row & 7) << 4));
            __builtin_amdgcn_global_load_lds(gp, &lds[i & 3][row * 256], 16, 0, 0);
        }
    };

    auto compute_store = [&](int i) __attribute__((always_inline)) {
        const char* lb = (const char*)&lds[i & 3][0] + col * 1024;
        f32x4 acc0 = (f32x4){0.f, 0.f, 0.f, 0.f};
        f32x4 acc1 = (f32x4){0.f, 0.f, 0.f, 0.f};
        #pragma unroll
        for (int ks = 0; ks < 8; ++ks) {
            int c = 32 * g + 128 * ks;
            f32x4 lo = *(const f32x4*)(lb + (c ^ xr));
            f32x4 hi = *(const f32x4*)(lb + ((c + 16) ^ xr));
            bf16x8 a;
            #pragma unroll
            for (int j = 0; j < 4; ++j) {
                a[j]     = (__bf16)lo[j];
                a[4 + j] = (__bf16)hi[j];
            }
            acc0 = __builtin_amdgcn_mfma_f32_16x16x32_bf16(
                __builtin_bit_cast(bf16x8, bfr[0][ks]), a, acc0, 0, 0, 0);
            acc1 = __builtin_amdgcn_mfma_f32_16x16x32_bf16(
                __builtin_bit_cast(bf16x8, bfr[1][ks]), a, acc1, 0, 0, 0);
        }
        float* orow = out + ((size_t)(bid + (size_t)i * G) * 16 + col) * D + n0;
        *(f32x4*)(orow + 4 * g)      = acc0 + avv[0];
        *(f32x4*)(orow + 16 + 4 * g) = acc1 + avv[1];
    };

    #define BAR()                                   \
        __builtin_amdgcn_sched_barrier(0);          \
        __builtin_amdgcn_s_barrier();               \
        __builtin_amdgcn_sched_barrier(0)

    for (int rep = 0; rep < REPS; ++rep) {
        asm volatile("s_waitcnt vmcnt(0) lgkmcnt(0)" ::: "memory");
        BAR();

        stage(0); stage(1); stage(2);

        // prologue steps 0..2 (waits: 4,6,8)
        WAITV(4); BAR(); stage(3);
        __builtin_amdgcn_sched_barrier(0);
        compute_store(0);
        WAITV(6); BAR(); stage(4);
        __builtin_amdgcn_sched_barrier(0);
        compute_store(1);
        WAITV(8); BAR(); stage(5);
        __builtin_amdgcn_sched_barrier(0);
        compute_store(2);

        // steady steps 3..29 (wait 10); step 29 issues no stage (i+3==32)
        for (int i = 3; i <= 29; ++i) {
            WAITV(10); BAR();
            if (i + 3 < NSTEP) stage(i + 3);
            __builtin_amdgcn_sched_barrier(0);
            compute_store(i);
        }

        // tail steps 30,31 (waits: 8,6)
        WAITV(8); BAR();
        compute_store(30);
        WAITV(6); BAR();
        compute_store(31);
    }
    #undef BAR
}

// ================= launch ================================================

extern "C" void kernel_launch(void* const* d_in, const int* in_sizes, int n_in,
                              void* d_out, int out_size, void* d_ws, size_t ws_size,
                              hipStream_t stream) {
    const float* X  = (const float*)d_in[0];
    const float* A  = (const float*)d_in[1];
    const float* b  = (const float*)d_in[2];
    const int*   t0 = (const int*)d_in[3];
    const int*   tf = (const int*)d_in[4];
    float* out = (float*)d_out;

    float* ws = (float*)d_ws;
    float* Ms = ws + 0 * PD2;
    float* M2 = ws + 1 * PD2;
    float* M3 = ws + 2 * PD2;
    float* M4 = ws + 3 * PD2;
    float* W  = ws + 4 * PD2;
    __bf16* PhiB = (__bf16*)(ws + 5 * PD2);
    float*  aff  = ws + 5 * PD2 + (D * D) / 2;

    const int g1 = (PD2 + 255) / 256;

    expm_mm1<<<g1, 256, 0, stream>>>(A, b, t0, tf, Ms, M2);
    expm_mm2<<<g1, 256, 0, stream>>>(Ms, M2, M3, M4, W);
    expm_mm3<<<g1, 256, 0, stream>>>(M4, W, Ms, M2, M3, PhiB, aff);

    gemm_out<<<G, 512, 0, stream>>>(X, PhiB, aff, out);
}

// Round 11
// 145.002 us; speedup vs baseline: 1.9806x; 1.8346x over previous
//
#include <hip/hip_runtime.h>
#include <hip/hip_bf16.h>

#define PD 272            // padded expm dim (257 -> 272)
#define PD2 (PD*PD)       // 73984
#define D 256
#define BATCH 262144
#define NT (BATCH/16)     // 16384 16-row tiles
#define G 512             // gemm grid: 2 blocks/CU, 32 tiles/block
#define NSTEP (NT/G)      // 32

typedef __bf16 bf16x8 __attribute__((ext_vector_type(8)));
typedef float  f32x4  __attribute__((ext_vector_type(4)));

#define WAITV(n) asm volatile("s_waitcnt vmcnt(" #n ")" ::: "memory")

// ================= expm chain (fp32, 272-padded, 3 kernels) ==============
// ||M*dt|| ~ 1.6 -> degree-8 Paterson-Stockmeyer Taylor, remainder ~9e-4
// << bf16 rounding of Phi. E = (c0I+c1M+c2M2+c3M3) + M4*W,
// W = c4I+c5M+c6M2+c7M3+c8M4, M4 = M2^2.

__device__ __forceinline__ float dotPD(const float* __restrict__ xr,
                                       const float* __restrict__ yc) {
    float a[16];
    #pragma unroll
    for (int u = 0; u < 16; ++u) a[u] = 0.f;
    #pragma unroll 2
    for (int k0 = 0; k0 < PD; k0 += 16) {
        #pragma unroll
        for (int u = 0; u < 16; ++u)
            a[u] = fmaf(xr[k0 + u], yc[(size_t)(k0 + u) * PD], a[u]);
    }
    float s = 0.f;
    #pragma unroll
    for (int u = 0; u < 16; ++u) s += a[u];
    return s;
}

// e1: Ms = M*dt (on the fly); M2 = Ms^2
__global__ void expm_mm1(const float* __restrict__ A, const float* __restrict__ b,
                         const int* __restrict__ t0, const int* __restrict__ tf,
                         float* __restrict__ Ms, float* __restrict__ M2) {
    int idx = blockIdx.x * blockDim.x + threadIdx.x;
    if (idx >= PD2) return;
    int i = idx / PD, j = idx - i * PD;
    float sc = (float)(tf[0] - t0[0]);
    float mv = 0.f;
    if (i < D && j < D) mv = A[i * D + j] * sc;
    else if (i < D && j == D) mv = b[i] * sc;
    Ms[idx] = mv;
    float acc = 0.f;
    if (i < D && j <= D) {
        const float* xr = A + (size_t)i * D;
        float a[16];
        #pragma unroll
        for (int u = 0; u < 16; ++u) a[u] = 0.f;
        if (j < D) {
            const float* yc = A + j;
            #pragma unroll 2
            for (int k0 = 0; k0 < D; k0 += 16) {
                #pragma unroll
                for (int u = 0; u < 16; ++u)
                    a[u] = fmaf(xr[k0 + u], yc[(size_t)(k0 + u) * D], a[u]);
            }
        } else {
            for (int k0 = 0; k0 < D; k0 += 16) {
                #pragma unroll
                for (int u = 0; u < 16; ++u)
                    a[u] = fmaf(xr[k0 + u], b[k0 + u], a[u]);
            }
        }
        float s = 0.f;
        #pragma unroll
        for (int u = 0; u < 16; ++u) s += a[u];
        acc = s * sc * sc;
    }
    M2[idx] = acc;
}

// e2: dual-dot off one shared M2-row stream:
//   M3 = M2*Ms, M4 = M2*M2, W = c4I+c5Ms+c6M2+c7M3+c8M4
__global__ void expm_mm2(const float* __restrict__ Ms, const float* __restrict__ M2,
                         float* __restrict__ M3, float* __restrict__ M4,
                         float* __restrict__ W) {
    int idx = blockIdx.x * blockDim.x + threadIdx.x;
    if (idx >= PD2) return;
    int i = idx / PD, j = idx - i * PD;
    const float* xr = M2 + (size_t)i * PD;
    const float* y3 = Ms + j;
    const float* y4 = M2 + j;
    float a3[8], a4[8];
    #pragma unroll
    for (int u = 0; u < 8; ++u) { a3[u] = 0.f; a4[u] = 0.f; }
    #pragma unroll 2
    for (int k0 = 0; k0 < PD; k0 += 8) {
        #pragma unroll
        for (int u = 0; u < 8; ++u) {
            float xv = xr[k0 + u];
            a3[u] = fmaf(xv, y3[(size_t)(k0 + u) * PD], a3[u]);
            a4[u] = fmaf(xv, y4[(size_t)(k0 + u) * PD], a4[u]);
        }
    }
    float v3 = ((a3[0]+a3[1])+(a3[2]+a3[3])) + ((a3[4]+a3[5])+(a3[6]+a3[7]));
    float v4 = ((a4[0]+a4[1])+(a4[2]+a4[3])) + ((a4[4]+a4[5])+(a4[6]+a4[7]));
    M3[idx] = v3;
    M4[idx] = v4;
    const float c4 = 1.f/24.f, c5 = 1.f/120.f, c6 = 1.f/720.f,
                c7 = 1.f/5040.f, c8 = 1.f/40320.f;
    float w = (i == j) ? c4 : 0.f;
    w = fmaf(c5, Ms[idx], w);
    w = fmaf(c6, M2[idx], w);
    w = fmaf(c7, v3, w);
    w = fmaf(c8, v4, w);
    W[idx] = w;
}

// e3: E = c0I+c1Ms+c2M2+c3M3 + M4*W; emit PhiB (bf16 [n][k]) + aff directly
__global__ void expm_mm3(const float* __restrict__ M4, const float* __restrict__ W,
                         const float* __restrict__ Ms, const float* __restrict__ M2,
                         const float* __restrict__ M3,
                         __bf16* __restrict__ PhiB, float* __restrict__ aff) {
    int idx = blockIdx.x * blockDim.x + threadIdx.x;
    if (idx >= PD2) return;
    int i = idx / PD, j = idx - i * PD;
    if (i >= D || j > D) return;
    float v = dotPD(M4 + (size_t)i * PD, W + j);
    float e = (i == j) ? 1.f : 0.f;
    e += Ms[idx];
    e = fmaf(0.5f, M2[idx], e);
    e = fmaf(1.f/6.f, M3[idx], e);
    e += v;
    if (j < D) PhiB[i * D + j] = (__bf16)e;
    else       aff[i] = e;
}

// ================= main GEMM =============================================
// out[m][n] = sum_k X[m][k]*Phi[n][k] + aff[n]
// R6 structure + CONTIGUOUS STORES via LDS out-stage.
// R10 diagnosis: step=9300cyc = HBM share (6530) + LDS (3070) serial; writes
// were 16x64B-scattered per instruction (MFMA D-layout), halving write-side
// HBM efficiency. Fix: acc -> LDS_out[16][256] (XOR-swizzled, conflict-free
// at the b128 8-phase minimum), barrier, wave reads one full row linearly,
// stores 1KB contiguous per instruction.
// Ring-3 depth-2 prefetch (depth doesn't matter, R10). vmcnt queue per step:
// [stage(i):2][store(i-2):2][stage(i+1):2][store(i-1):2] -> waits 2,4,6..6,4.
__global__ __launch_bounds__(512, 4) void gemm_out(
    const float* __restrict__ X, const __bf16* __restrict__ PhiB,
    const float* __restrict__ aff, float* __restrict__ out) {
    __shared__ float ring[3][4096];      // 3 x 16 KB in-tile ring
    __shared__ float outb[4096];         // 16 KB out-stage

    const int lane = threadIdx.x & 63;
    const int wid  = threadIdx.x >> 6;   // 0..7
    const int col  = lane & 15;          // X row within tile = D-col (m)
    const int g    = lane >> 4;          // k-group
    const int n0   = wid * 32;
    const int bid  = blockIdx.x;
    const int xr   = (col & 7) << 4;

    // ---- Phi fragments: 2 n-tiles x 8 ks, pinned in registers ----
    f32x4 bfr[2][8];
    #pragma unroll
    for (int t4 = 0; t4 < 2; ++t4) {
        const char* bp = (const char*)PhiB + (size_t)2 * ((n0 + t4 * 16 + col) * D + g * 8);
        #pragma unroll
        for (int ks = 0; ks < 8; ++ks)
            bfr[t4][ks] = *(const f32x4*)(bp + 2 * ks * 32);
    }
    #pragma unroll
    for (int t4 = 0; t4 < 2; ++t4)
        #pragma unroll
        for (int ks = 0; ks < 8; ++ks)
            asm volatile("" : "+v"(bfr[t4][ks]));

    f32x4 avv[2];
    #pragma unroll
    for (int t4 = 0; t4 < 2; ++t4)
        avv[t4] = *(const f32x4*)(aff + n0 + t4 * 16 + 4 * g);
    #pragma unroll
    for (int t4 = 0; t4 < 2; ++t4) asm volatile("" : "+v"(avv[t4]));

    // stage tile i (tile id = bid + i*G) into ring buf i%3 (1KB/row, contig)
    auto stage = [&](int i) __attribute__((always_inline)) {
        const char* src = (const char*)(X + (size_t)(bid + (size_t)i * G) * 4096);
        #pragma unroll
        for (int q = 0; q < 2; ++q) {
            int row = wid * 2 + q;
            const char* gp = src + row * 1024 + ((lane * 16) ^ ((row & 7) << 4));
            __builtin_amdgcn_global_load_lds(gp, &ring[i % 3][row * 256], 16, 0, 0);
        }
    };

    // MFMA for tile i's buffer; write result into outb (swizzled)
    auto compute = [&](int i) __attribute__((always_inline)) {
        const char* lb = (const char*)&ring[i % 3][0] + col * 1024;
        f32x4 acc0 = (f32x4){0.f, 0.f, 0.f, 0.f};
        f32x4 acc1 = (f32x4){0.f, 0.f, 0.f, 0.f};
        #pragma unroll
        for (int ks = 0; ks < 8; ++ks) {
            int c = 32 * g + 128 * ks;
            f32x4 lo = *(const f32x4*)(lb + (c ^ xr));
            f32x4 hi = *(const f32x4*)(lb + ((c + 16) ^ xr));
            bf16x8 a;
            #pragma unroll
            for (int j = 0; j < 4; ++j) {
                a[j]     = (__bf16)lo[j];
                a[4 + j] = (__bf16)hi[j];
            }
            acc0 = __builtin_amdgcn_mfma_f32_16x16x32_bf16(
                __builtin_bit_cast(bf16x8, bfr[0][ks]), a, acc0, 0, 0, 0);
            acc1 = __builtin_amdgcn_mfma_f32_16x16x32_bf16(
                __builtin_bit_cast(bf16x8, bfr[1][ks]), a, acc1, 0, 0, 0);
        }
        // outb[row=col][byte: wid*128 + t4*64 + g*16], XOR (col&7)<<4.
        // Conflict-free: bank-quad = (t4*4+g)^(col&7) bijective per 8-lane grp.
        char* ob = (char*)outb + col * 1024;
        *(f32x4*)(ob + ((wid * 128 + g * 16) ^ xr))      = acc0 + avv[0];
        *(f32x4*)(ob + ((wid * 128 + 64 + g * 16) ^ xr)) = acc1 + avv[1];
    };

    // read back 2 full rows linearly, store 1KB-contiguous per instruction
    auto flush = [&](int i) __attribute__((always_inline)) {
        #pragma unroll
        for (int q = 0; q < 2; ++q) {
            int row = wid * 2 + q;
            f32x4 v = *(const f32x4*)((const char*)outb + row * 1024
                                      + ((lane * 16) ^ ((row & 7) << 4)));
            float* dst = out + ((size_t)(bid + (size_t)i * G) * 16 + row) * D + lane * 4;
            *(f32x4*)dst = v;
        }
    };

    #define BAR()                                   \
        __builtin_amdgcn_sched_barrier(0);          \
        __builtin_amdgcn_s_barrier();               \
        __builtin_amdgcn_sched_barrier(0)

    stage(0); stage(1);

    for (int i = 0; i < NSTEP; ++i) {
        // wait: stage(i) complete (exact in-order queue; see header comment)
        if (i == 0)            { WAITV(2); }
        else if (i == 1)       { WAITV(4); }
        else if (i < NSTEP-1)  { WAITV(6); }
        else                   { WAITV(4); }
        BAR();                               // ring[i%3] ready; outb free
        if (i + 2 < NSTEP) stage(i + 2);
        __builtin_amdgcn_sched_barrier(0);
        compute(i);
        asm volatile("s_waitcnt lgkmcnt(0)" ::: "memory");
        BAR();                               // outb fully written
        flush(i);
    }
    #undef BAR
}

// ================= launch ================================================

extern "C" void kernel_launch(void* const* d_in, const int* in_sizes, int n_in,
                              void* d_out, int out_size, void* d_ws, size_t ws_size,
                              hipStream_t stream) {
    const float* X  = (const float*)d_in[0];
    const float* A  = (const float*)d_in[1];
    const float* b  = (const float*)d_in[2];
    const int*   t0 = (const int*)d_in[3];
    const int*   tf = (const int*)d_in[4];
    float* out = (float*)d_out;

    float* ws = (float*)d_ws;
    float* Ms = ws + 0 * PD2;
    float* M2 = ws + 1 * PD2;
    float* M3 = ws + 2 * PD2;
    float* M4 = ws + 3 * PD2;
    float* W  = ws + 4 * PD2;
    __bf16* PhiB = (__bf16*)(ws + 5 * PD2);
    float*  aff  = ws + 5 * PD2 + (D * D) / 2;

    const int g1 = (PD2 + 255) / 256;

    expm_mm1<<<g1, 256, 0, stream>>>(A, b, t0, tf, Ms, M2);
    expm_mm2<<<g1, 256, 0, stream>>>(Ms, M2, M3, M4, W);
    expm_mm3<<<g1, 256, 0, stream>>>(M4, W, Ms, M2, M3, PhiB, aff);

    gemm_out<<<G, 512, 0, stream>>>(X, PhiB, aff, out);
}